// Round 2
// baseline (287.912 us; speedup 1.0000x reference)
//
#include <hip/hip_runtime.h>
#include <math.h>

#define D_PROJ 8192
#define C_IN   512
#define P_SP   196   // 14*14
#define NBATCH 32

// ---------------------------------------------------------------------------
// Recover both count-sketches in one pass. S1,S2: [512, 8192], one nonzero
// (+-1) per row at column h[row]. Writes packed  h | (s<0 ? 0x8000 : 0).
// float4 grid-stride over both matrices (33.5 MB total -> ~7 us).
// ---------------------------------------------------------------------------
__global__ __launch_bounds__(256) void extract_both(
    const float* __restrict__ S1, const float* __restrict__ S2,
    int* __restrict__ p1, int* __restrict__ p2)
{
    const int total4 = 2 * C_IN * (D_PROJ / 4);      // 2,097,152 float4
    for (int idx = blockIdx.x * 256 + threadIdx.x; idx < total4;
         idx += gridDim.x * 256) {
        const int m   = idx >> 20;                   // 0: S1, 1: S2
        const int rem = idx & 1048575;
        const float4 v = ((const float4*)(m ? S2 : S1))[rem];
        if (v.x != 0.f || v.y != 0.f || v.z != 0.f || v.w != 0.f) {
            const int row = rem >> 11;               // 2048 float4 per row
            const int c4  = (rem & 2047) << 2;
            float val; int c;
            if      (v.x != 0.f) { val = v.x; c = c4;     }
            else if (v.y != 0.f) { val = v.y; c = c4 + 1; }
            else if (v.z != 0.f) { val = v.z; c = c4 + 2; }
            else                 { val = v.w; c = c4 + 3; }
            const int packed = c | (val < 0.f ? 0x8000 : 0);
            (m ? p2 : p1)[row] = packed;
        }
    }
}

// ---------------------------------------------------------------------------
// x[b][c][p] -> xT[b][p][c]  (p = 196, c = 512). Enables float4-coalesced,
// div-free staging in the gram kernel.
// ---------------------------------------------------------------------------
__global__ __launch_bounds__(256) void transpose_x(
    const float* __restrict__ x, float* __restrict__ xT)
{
    __shared__ float tile[32][33];
    const int b  = blockIdx.z;
    const int c0 = blockIdx.y * 32;
    const int p0 = blockIdx.x * 32;
    const int tx = threadIdx.x & 31;
    const int ty = threadIdx.x >> 5;
    #pragma unroll
    for (int k = 0; k < 4; ++k) {
        const int p = p0 + tx, c = c0 + ty + k * 8;
        if (p < P_SP) tile[ty + k * 8][tx] = x[((size_t)b * C_IN + c) * P_SP + p];
    }
    __syncthreads();
    #pragma unroll
    for (int k = 0; k < 4; ++k) {
        const int p = p0 + ty + k * 8, c = c0 + tx;
        if (p < P_SP) xT[((size_t)b * P_SP + p) * C_IN + c] = tile[tx][ty + k * 8];
    }
}

// ---------------------------------------------------------------------------
// Fused Gram + count-sketch scatter. Block = (jt, it, b*2+kh); 128x128 G tile
// over a 98-deep K half (14 chunks of 7), 8x8 register microtile, then LDS
// 8192-bin histogram scatter, global-atomic flush into pool (= d_out).
// LDS = 32768 (hist) + 2*3584 (staging) + 512 (packed params) = 40448 B
// -> 4 blocks/CU with __launch_bounds__(256,4).
// ---------------------------------------------------------------------------
#define PCH 7

__global__ __launch_bounds__(256, 4) void gram_scatter(
    const float* __restrict__ xT,
    const int* __restrict__ P1, const int* __restrict__ P2,
    float* __restrict__ pool)
{
    __shared__ float hist[D_PROJ];                       // 32 KB
    __shared__ __align__(16) float As[PCH * 128];        // 3.5 KB, p-major
    __shared__ __align__(16) float Bs[PCH * 128];
    __shared__ unsigned short p1L[128], p2L[128];        // packed h|sign<<15

    const int tid = threadIdx.x;
    const int tx  = tid & 15;           // j quad
    const int ty  = tid >> 4;           // i quad
    const int jt  = blockIdx.x;         // j tile (0..3)
    const int it  = blockIdx.y;         // i tile (0..3)
    const int b   = blockIdx.z >> 1;
    const int kh  = blockIdx.z & 1;     // K half (p in [kh*98, kh*98+98))

    if (tid < 128) {
        p1L[tid] = (unsigned short)P1[it * 128 + tid];
        p2L[tid] = (unsigned short)P2[jt * 128 + tid];
    }
    {   // zero histogram (float4)
        float4* h4 = (float4*)hist;
        const float4 z = make_float4(0.f, 0.f, 0.f, 0.f);
        #pragma unroll
        for (int k = 0; k < 8; ++k) h4[tid + k * 256] = z;
    }

    const float* xb = xT + (size_t)b * P_SP * C_IN;
    const int iofs = it * 128, jofs = jt * 128;

    float acc[8][8];
    #pragma unroll
    for (int r = 0; r < 8; ++r)
        #pragma unroll
        for (int c = 0; c < 8; ++c) acc[r][c] = 0.0f;

    for (int ck = 0; ck < 14; ++ck) {
        const int p0 = kh * 98 + ck * PCH;
        __syncthreads();   // 1st iter: covers hist zero + param staging
        // stage: 2*224 float4; thread t -> f=t (A if f<224 else B), f=t+256 (B)
        if (tid < 224) {
            const int pp = tid >> 5, cc = (tid & 31) * 4;
            *(float4*)(As + pp * 128 + cc) =
                *(const float4*)(xb + (size_t)(p0 + pp) * C_IN + iofs + cc);
        } else {
            const int f = tid - 224;
            const int pp = f >> 5, cc = (f & 31) * 4;
            *(float4*)(Bs + pp * 128 + cc) =
                *(const float4*)(xb + (size_t)(p0 + pp) * C_IN + jofs + cc);
        }
        if (tid < 192) {
            const int f = tid + 32;
            const int pp = f >> 5, cc = (f & 31) * 4;
            *(float4*)(Bs + pp * 128 + cc) =
                *(const float4*)(xb + (size_t)(p0 + pp) * C_IN + jofs + cc);
        }
        __syncthreads();
        #pragma unroll
        for (int pp = 0; pp < PCH; ++pp) {
            const float* ap = As + pp * 128;
            const float* bp = Bs + pp * 128;
            const float4 a0 = *(const float4*)(ap + ty * 4);
            const float4 a1 = *(const float4*)(ap + 64 + ty * 4);
            const float4 b0 = *(const float4*)(bp + tx * 4);
            const float4 b1 = *(const float4*)(bp + 64 + tx * 4);
            const float av[8] = {a0.x, a0.y, a0.z, a0.w, a1.x, a1.y, a1.z, a1.w};
            const float bv[8] = {b0.x, b0.y, b0.z, b0.w, b1.x, b1.y, b1.z, b1.w};
            #pragma unroll
            for (int r = 0; r < 8; ++r)
                #pragma unroll
                for (int c = 0; c < 8; ++c)
                    acc[r][c] = fmaf(av[r], bv[c], acc[r][c]);
        }
    }

    // scatter: bin = (h1+h2)&8191; sign parity lives at bit 15 of the sum
    // (h1+h2 <= 16382 only uses bits 0..13, so no carry into bit 15).
    int pa[8], pb[8];
    #pragma unroll
    for (int r = 0; r < 8; ++r) {
        const int il = (r < 4) ? (ty * 4 + r) : (64 + ty * 4 + r - 4);
        pa[r] = p1L[il];
    }
    #pragma unroll
    for (int c = 0; c < 8; ++c) {
        const int jl = (c < 4) ? (tx * 4 + c) : (64 + tx * 4 + c - 4);
        pb[c] = p2L[jl];
    }
    #pragma unroll
    for (int r = 0; r < 8; ++r)
        #pragma unroll
        for (int c = 0; c < 8; ++c) {
            const int sum = pa[r] + pb[c];
            const int d   = sum & (D_PROJ - 1);
            const float v = __int_as_float(
                __float_as_int(acc[r][c]) ^ ((sum << 16) & 0x80000000));
            atomicAdd(&hist[d], v);
        }
    __syncthreads();

    float* pm = pool + (size_t)b * D_PROJ;
    for (int k = tid; k < D_PROJ; k += 256) atomicAdd(&pm[k], hist[k]);
}

// ---------------------------------------------------------------------------
// Per-batch: norm = sqrt(sum |pool| + 8192e-8); out = sign(p)*sqrt(|p|+1e-8)/norm
// ---------------------------------------------------------------------------
__global__ __launch_bounds__(256) void finalize_kernel(float* __restrict__ out)
{
    const int b = blockIdx.x;
    float4* p = (float4*)(out + (size_t)b * D_PROJ);
    const int tid = threadIdx.x;

    float4 v[8];
    float s = 0.0f;
    #pragma unroll
    for (int k = 0; k < 8; ++k) {
        v[k] = p[tid + k * 256];
        s += fabsf(v[k].x) + fabsf(v[k].y) + fabsf(v[k].z) + fabsf(v[k].w);
    }
    #pragma unroll
    for (int off = 32; off > 0; off >>= 1) s += __shfl_down(s, off, 64);

    __shared__ float red[4];
    if ((tid & 63) == 0) red[tid >> 6] = s;
    __syncthreads();
    const float total = red[0] + red[1] + red[2] + red[3];
    const float inv = 1.0f / fmaxf(sqrtf(total + (float)D_PROJ * 1e-8f), 1e-12f);

    #pragma unroll
    for (int k = 0; k < 8; ++k) {
        float4 w = v[k];
        float* e = (float*)&w;
        #pragma unroll
        for (int q = 0; q < 4; ++q) {
            const float x = e[q];
            const float r = sqrtf(fabsf(x) + 1e-8f) * inv;
            e[q] = (x > 0.f) ? r : ((x < 0.f) ? -r : 0.f);
        }
        p[tid + k * 256] = w;
    }
}

// ---------------------------------------------------------------------------
extern "C" void kernel_launch(void* const* d_in, const int* in_sizes, int n_in,
                              void* d_out, int out_size, void* d_ws, size_t ws_size,
                              hipStream_t stream)
{
    const float* x  = (const float*)d_in[0];   // [32, 512, 14, 14]
    const float* S1 = (const float*)d_in[1];   // [512, 8192]
    const float* S2 = (const float*)d_in[2];   // [512, 8192]
    float* out = (float*)d_out;                // [32, 8192]

    char* ws = (char*)d_ws;
    int*   p1 = (int*)(ws);                    // 2 KB packed sketch 1
    int*   p2 = (int*)(ws + 2048);             // 2 KB packed sketch 2
    float* xT = (float*)(ws + 8192);           // 12.8 MB transposed x

    hipMemsetAsync(d_out, 0, (size_t)out_size * sizeof(float), stream);
    extract_both<<<1024, 256, 0, stream>>>(S1, S2, p1, p2);
    transpose_x<<<dim3(7, 16, NBATCH), 256, 0, stream>>>(x, xT);
    gram_scatter<<<dim3(4, 4, NBATCH * 2), 256, 0, stream>>>(xT, p1, p2, out);
    finalize_kernel<<<NBATCH, 256, 0, stream>>>(out);
}